// Round 2
// 454.645 us; speedup vs baseline: 1.1756x; 1.1756x over previous
//
#include <hip/hip_runtime.h>

#define N_USERS 200000
#define N_ITEMS 100000
#define N_NODES 300000
#define DIM 64
#define N_INTER 1000000

#define BSHIFT 10                      // 1024 nodes per bucket
#define BNODES (1 << BSHIFT)
#define NBUCKET ((N_NODES + BNODES - 1) >> BSHIFT)   // 293
#define TILE 4096                      // interactions per block in hist/place
#define NBLK_P ((N_INTER + TILE - 1) / TILE)          // 245

typedef unsigned short bf16_t;
typedef unsigned int u32;

static __device__ __forceinline__ bf16_t f2bf(float f) {
    union { float f; u32 u; } v; v.f = f;
    u32 r = v.u + 0x7FFFu + ((v.u >> 16) & 1u);
    return (bf16_t)(r >> 16);
}
static __device__ __forceinline__ float bf2f(bf16_t h) {
    union { u32 u; float f; } v; v.u = ((u32)h) << 16;
    return v.f;
}

// ---------------- 1. bucket histogram (LDS, then one merge per bucket) ----------------
__global__ void hist_kernel(const int* __restrict__ uid, const int* __restrict__ iid,
                            u32* __restrict__ bucket_count) {
    __shared__ u32 h[NBUCKET];
    int t = threadIdx.x;
    for (int i = t; i < NBUCKET; i += 256) h[i] = 0;
    __syncthreads();
    int base = blockIdx.x * TILE;
    int end = base + TILE; if (end > N_INTER) end = N_INTER;
    for (int k = base + t; k < end; k += 256) {
        int u = uid[k];
        int it = N_USERS + iid[k];
        atomicAdd(&h[it >> BSHIFT], 1u);   // edge u->it lands in it's bucket
        atomicAdd(&h[u >> BSHIFT], 1u);    // edge it->u lands in u's bucket
    }
    __syncthreads();
    for (int i = t; i < NBUCKET; i += 256)
        if (h[i]) atomicAdd(&bucket_count[i], h[i]);
}

// ---------------- 2. scan bucket counts -> bstart, init cursors ----------------
__global__ void scan_kernel(const u32* __restrict__ bucket_count, u32* __restrict__ bstart,
                            u32* __restrict__ bucket_cursor, u32* __restrict__ rowptr) {
    __shared__ u32 buf[2][512];
    int t = threadIdx.x;  // 512 threads
    u32 v0 = (t < NBUCKET) ? bucket_count[t] : 0u;
    buf[0][t] = v0;
    __syncthreads();
    int s = 0;
    for (int off = 1; off < 512; off <<= 1) {
        u32 v = buf[s][t];
        if (t >= off) v += buf[s][t - off];
        buf[1 - s][t] = v;
        __syncthreads();
        s = 1 - s;
    }
    if (t < NBUCKET) {
        u32 excl = buf[s][t] - v0;
        bstart[t] = excl;
        bucket_cursor[t] = excl;
    }
    if (t == 0) {
        bstart[NBUCKET] = 2 * N_INTER;
        rowptr[N_NODES] = 2 * N_INTER;
    }
}

// ---------------- 3. place: exact per-(block,bucket) reservations ----------------
// entry = (local_dst << 19) | src   (src < 2^19, local_dst < 1024 -> bits 19..28)
__global__ void place_kernel(const int* __restrict__ uid, const int* __restrict__ iid,
                             u32* __restrict__ bucket_cursor, u32* __restrict__ bdata) {
    __shared__ u32 h[NBUCKET];      // pass1: counts; pass2: local cursor
    __shared__ u32 basesh[NBUCKET]; // reserved global base per bucket
    int t = threadIdx.x;
    for (int i = t; i < NBUCKET; i += 256) h[i] = 0;
    __syncthreads();
    int base = blockIdx.x * TILE;
    int end = base + TILE; if (end > N_INTER) end = N_INTER;
    // pass 1: local histogram
    for (int k = base + t; k < end; k += 256) {
        int u = uid[k];
        int it = N_USERS + iid[k];
        atomicAdd(&h[it >> BSHIFT], 1u);
        atomicAdd(&h[u >> BSHIFT], 1u);
    }
    __syncthreads();
    // reserve ranges
    for (int i = t; i < NBUCKET; i += 256) {
        u32 c = h[i];
        basesh[i] = c ? atomicAdd(&bucket_cursor[i], c) : 0u;
        h[i] = 0;
    }
    __syncthreads();
    // pass 2: place
    for (int k = base + t; k < end; k += 256) {
        int u = uid[k];
        int it = N_USERS + iid[k];
        {
            int b = it >> BSHIFT;
            u32 pos = basesh[b] + atomicAdd(&h[b], 1u);
            bdata[pos] = (((u32)(it & (BNODES - 1))) << 19) | (u32)u;
        }
        {
            int b = u >> BSHIFT;
            u32 pos = basesh[b] + atomicAdd(&h[b], 1u);
            bdata[pos] = (((u32)(u & (BNODES - 1))) << 19) | (u32)it;
        }
    }
}

// ---------------- 4. per-bucket CSR finalize: rowptr, dinv, col ----------------
__global__ void csr_kernel(const u32* __restrict__ bstart, const u32* __restrict__ bdata,
                           u32* __restrict__ rowptr, float* __restrict__ dinv,
                           int* __restrict__ col) {
    __shared__ u32 cnt[BNODES];
    __shared__ u32 sb[2][BNODES];
    __shared__ u32 cur[BNODES];
    int b = blockIdx.x;
    int t = threadIdx.x;               // 256 threads
    int nbase = b << BSHIFT;
    u32 bs = bstart[b], be = bstart[b + 1];
    u32 m = be - bs;

    #pragma unroll
    for (int j = 0; j < 4; ++j) cnt[t + j * 256] = 0;
    __syncthreads();
    // pass A: count per local node
    for (u32 e = t; e < m; e += 256) {
        u32 v = bdata[bs + e];
        atomicAdd(&cnt[v >> 19], 1u);
    }
    __syncthreads();
    // inclusive scan of 1024 (Hillis-Steele, 4 elems/thread)
    #pragma unroll
    for (int j = 0; j < 4; ++j) sb[0][t + j * 256] = cnt[t + j * 256];
    __syncthreads();
    int s = 0;
    for (int off = 1; off < BNODES; off <<= 1) {
        #pragma unroll
        for (int j = 0; j < 4; ++j) {
            int idx = t + j * 256;
            u32 v = sb[s][idx];
            if (idx >= off) v += sb[s][idx - off];
            sb[1 - s][idx] = v;
        }
        __syncthreads();
        s = 1 - s;
    }
    // rowptr, dinv, cursors
    #pragma unroll
    for (int j = 0; j < 4; ++j) {
        int idx = t + j * 256;
        int node = nbase + idx;
        u32 c = cnt[idx];
        u32 excl = sb[s][idx] - c;
        cur[idx] = excl;
        if (node < N_NODES) {
            rowptr[node] = bs + excl;
            dinv[node] = (c > 0) ? rsqrtf((float)c) : 0.0f;
        }
    }
    __syncthreads();
    // pass B: place col entries into contiguous [bs, be)
    for (u32 e = t; e < m; e += 256) {
        u32 v = bdata[bs + e];
        u32 ln = v >> 19;
        u32 pos = atomicAdd(&cur[ln], 1u);
        col[bs + pos] = (int)(v & 0x7FFFFu);
    }
}

// ---------------- 5. edge records: (src, dinv[src]) ----------------
__global__ void ecol_kernel(const int* __restrict__ col, const float* __restrict__ dinv,
                            int2* __restrict__ ecol) {
    int e = blockIdx.x * blockDim.x + threadIdx.x;
    if (e < 2 * N_INTER) {
        int s = col[e];
        ecol[e] = make_int2(s, __float_as_int(dinv[s]));
    }
}

// ---------------- init: fp32 inputs -> bf16 layer-0 buffer ----------------
__global__ void init_kernel(const float4* __restrict__ ue, const float4* __restrict__ ie,
                            ushort4* __restrict__ cur) {
    int idx = blockIdx.x * blockDim.x + threadIdx.x;
    if (idx < N_NODES * 16) {
        float4 v = (idx < N_USERS * 16) ? ue[idx] : ie[idx - N_USERS * 16];
        ushort4 h;
        h.x = f2bf(v.x); h.y = f2bf(v.y); h.z = f2bf(v.z); h.w = f2bf(v.w);
        cur[idx] = h;
    }
}

// ---------------- gather SpMM: one wave per node, scalar-broadcast 8-deep batches ----------------
// n is forced wave-uniform (readfirstlane) so rowptr/dinv become s_loads and the
// per-edge (src, w) broadcast is v_readlane (VALU->SGPR, no DS round-trip).
// Edges are processed in masked 8-wide batches: 8 independent 128B gather loads
// issued back-to-back per batch (MLP=8/wave), no serial tail loop. Masked slots
// read row 0 (L1 broadcast hit) with w=0.
__global__ void gather_kernel(const u32* __restrict__ rowptr, const int2* __restrict__ ecol,
                              const float* __restrict__ dinv,
                              const bf16_t* __restrict__ cur, bf16_t* __restrict__ nxt) {
    int n = (blockIdx.x * blockDim.x + threadIdx.x) >> 6;
    int lane = threadIdx.x & 63;
    n = __builtin_amdgcn_readfirstlane(n);
    if (n >= N_NODES) return;
    u32 start = rowptr[n], end = rowptr[n + 1];
    float acc = 0.0f;
    for (u32 base = start; base < end; base += 64) {
        int cnt = (int)(end - base); if (cnt > 64) cnt = 64;
        int2 e = make_int2(0, 0);
        if (lane < cnt) e = ecol[base + lane];
        for (int j = 0; j < cnt; j += 8) {
            int s[8], w[8];
            #pragma unroll
            for (int k = 0; k < 8; ++k) {
                int lidx = __builtin_amdgcn_readfirstlane(j + k);  // uniform lane select
                s[k] = __builtin_amdgcn_readlane(e.x, lidx);
                w[k] = __builtin_amdgcn_readlane(e.y, lidx);
            }
            float r[8];
            #pragma unroll
            for (int k = 0; k < 8; ++k)
                r[k] = bf2f(cur[((u32)s[k] << 6) + lane]);
            #pragma unroll
            for (int k = 0; k < 8; ++k)
                acc += __int_as_float(w[k]) * r[k];
        }
    }
    nxt[((u32)n << 6) + lane] = f2bf(dinv[n] * acc);
}

// ---------------- layer-3 gather fused with final combine ----------------
__global__ void gather_final_kernel(const u32* __restrict__ rowptr, const int2* __restrict__ ecol,
                                    const float* __restrict__ dinv,
                                    const bf16_t* __restrict__ b1, const bf16_t* __restrict__ b2,
                                    const float* __restrict__ ue, const float* __restrict__ ie,
                                    float* __restrict__ out) {
    int n = (blockIdx.x * blockDim.x + threadIdx.x) >> 6;
    int lane = threadIdx.x & 63;
    n = __builtin_amdgcn_readfirstlane(n);
    if (n >= N_NODES) return;
    u32 start = rowptr[n], end = rowptr[n + 1];
    float acc = 0.0f;
    for (u32 base = start; base < end; base += 64) {
        int cnt = (int)(end - base); if (cnt > 64) cnt = 64;
        int2 e = make_int2(0, 0);
        if (lane < cnt) e = ecol[base + lane];
        for (int j = 0; j < cnt; j += 8) {
            int s[8], w[8];
            #pragma unroll
            for (int k = 0; k < 8; ++k) {
                int lidx = __builtin_amdgcn_readfirstlane(j + k);  // uniform lane select
                s[k] = __builtin_amdgcn_readlane(e.x, lidx);
                w[k] = __builtin_amdgcn_readlane(e.y, lidx);
            }
            float r[8];
            #pragma unroll
            for (int k = 0; k < 8; ++k)
                r[k] = bf2f(b2[((u32)s[k] << 6) + lane]);
            #pragma unroll
            for (int k = 0; k < 8; ++k)
                acc += __int_as_float(w[k]) * r[k];
        }
    }
    float r = dinv[n] * acc;
    u32 o = ((u32)n << 6) + lane;
    float e0 = (n < N_USERS) ? ue[o] : ie[o - (u32)N_USERS * DIM];
    out[o] = (e0 + bf2f(b1[o]) + bf2f(b2[o]) + r) * 0.25f;
}

extern "C" void kernel_launch(void* const* d_in, const int* in_sizes, int n_in,
                              void* d_out, int out_size, void* d_ws, size_t ws_size,
                              hipStream_t stream) {
    const float* ue = (const float*)d_in[0];
    const float* ie = (const float*)d_in[1];
    const int* uid = (const int*)d_in[2];
    const int* iid = (const int*)d_in[3];
    float* out = (float*)d_out;

    char* ws = (char*)d_ws;
    size_t off = 0;
    auto alloc = [&](size_t bytes) { char* p = ws + off; off = (off + bytes + 255) & ~(size_t)255; return p; };
    u32*    bucket_count  = (u32*)alloc((size_t)NBUCKET * 4);
    u32*    bstart        = (u32*)alloc((size_t)(NBUCKET + 1) * 4);
    u32*    bucket_cursor = (u32*)alloc((size_t)NBUCKET * 4);
    u32*    rowptr        = (u32*)alloc((size_t)(N_NODES + 1) * 4);
    float*  dinv          = (float*)alloc((size_t)N_NODES * 4);
    u32*    bdata         = (u32*)alloc((size_t)2 * N_INTER * 4);     // 8 MB
    int*    col           = (int*)alloc((size_t)2 * N_INTER * 4);     // 8 MB
    int2*   ecol          = (int2*)alloc((size_t)2 * N_INTER * 8);    // 16 MB
    bf16_t* buf0          = (bf16_t*)alloc((size_t)N_NODES * DIM * 2);
    bf16_t* buf1          = (bf16_t*)alloc((size_t)N_NODES * DIM * 2);
    bf16_t* buf2          = (bf16_t*)alloc((size_t)N_NODES * DIM * 2);

    // --- CSR build: exact-reservation bucketed, line-friendly writes throughout ---
    hipMemsetAsync(bucket_count, 0, (size_t)NBUCKET * 4, stream);
    hist_kernel<<<NBLK_P, 256, 0, stream>>>(uid, iid, bucket_count);
    scan_kernel<<<1, 512, 0, stream>>>(bucket_count, bstart, bucket_cursor, rowptr);
    place_kernel<<<NBLK_P, 256, 0, stream>>>(uid, iid, bucket_cursor, bdata);
    csr_kernel<<<NBUCKET, 256, 0, stream>>>(bstart, bdata, rowptr, dinv, col);
    ecol_kernel<<<(2 * N_INTER + 255) / 256, 256, 0, stream>>>(col, dinv, ecol);

    // --- init (fp32 -> bf16 layer 0) ---
    init_kernel<<<(N_NODES * 16 + 255) / 256, 256, 0, stream>>>(
        (const float4*)ue, (const float4*)ie, (ushort4*)buf0);

    // --- layers 1,2 gather; layer 3 fused with final combine ---
    gather_kernel<<<(N_NODES * 64 + 255) / 256, 256, 0, stream>>>(rowptr, ecol, dinv, buf0, buf1);
    gather_kernel<<<(N_NODES * 64 + 255) / 256, 256, 0, stream>>>(rowptr, ecol, dinv, buf1, buf2);
    gather_final_kernel<<<(N_NODES * 64 + 255) / 256, 256, 0, stream>>>(
        rowptr, ecol, dinv, buf1, buf2, ue, ie, out);
}

// Round 3
// 424.470 us; speedup vs baseline: 1.2592x; 1.0711x over previous
//
#include <hip/hip_runtime.h>

#define N_USERS 200000
#define N_ITEMS 100000
#define N_NODES 300000
#define DIM 64
#define N_INTER 1000000

#define BSHIFT 10                      // 1024 nodes per bucket
#define BNODES (1 << BSHIFT)
#define NBUCKET ((N_NODES + BNODES - 1) >> BSHIFT)   // 293
#define TILE 4096                      // interactions per block in hist/place
#define NBLK_P ((N_INTER + TILE - 1) / TILE)          // 245

#define NPW 8                          // nodes (rows) per wave in gather
#define NWAVE ((N_NODES + NPW - 1) / NPW)             // 37500
#define GATHER_THREADS (NWAVE * 64)                   // 2,400,000

typedef unsigned short bf16_t;
typedef unsigned int u32;

static __device__ __forceinline__ bf16_t f2bf(float f) {
    union { float f; u32 u; } v; v.f = f;
    u32 r = v.u + 0x7FFFu + ((v.u >> 16) & 1u);
    return (bf16_t)(r >> 16);
}
static __device__ __forceinline__ float bf2f(bf16_t h) {
    union { u32 u; float f; } v; v.u = ((u32)h) << 16;
    return v.f;
}

// ---------------- 1. bucket histogram (LDS, then one merge per bucket) ----------------
__global__ void hist_kernel(const int* __restrict__ uid, const int* __restrict__ iid,
                            u32* __restrict__ bucket_count) {
    __shared__ u32 h[NBUCKET];
    int t = threadIdx.x;
    for (int i = t; i < NBUCKET; i += 256) h[i] = 0;
    __syncthreads();
    int base = blockIdx.x * TILE;
    int end = base + TILE; if (end > N_INTER) end = N_INTER;
    for (int k = base + t; k < end; k += 256) {
        int u = uid[k];
        int it = N_USERS + iid[k];
        atomicAdd(&h[it >> BSHIFT], 1u);   // edge u->it lands in it's bucket
        atomicAdd(&h[u >> BSHIFT], 1u);    // edge it->u lands in u's bucket
    }
    __syncthreads();
    for (int i = t; i < NBUCKET; i += 256)
        if (h[i]) atomicAdd(&bucket_count[i], h[i]);
}

// ---------------- 2. scan bucket counts -> bstart, init cursors ----------------
__global__ void scan_kernel(const u32* __restrict__ bucket_count, u32* __restrict__ bstart,
                            u32* __restrict__ bucket_cursor, u32* __restrict__ rowptr) {
    __shared__ u32 buf[2][512];
    int t = threadIdx.x;  // 512 threads
    u32 v0 = (t < NBUCKET) ? bucket_count[t] : 0u;
    buf[0][t] = v0;
    __syncthreads();
    int s = 0;
    for (int off = 1; off < 512; off <<= 1) {
        u32 v = buf[s][t];
        if (t >= off) v += buf[s][t - off];
        buf[1 - s][t] = v;
        __syncthreads();
        s = 1 - s;
    }
    if (t < NBUCKET) {
        u32 excl = buf[s][t] - v0;
        bstart[t] = excl;
        bucket_cursor[t] = excl;
    }
    if (t == 0) {
        bstart[NBUCKET] = 2 * N_INTER;
        rowptr[N_NODES] = 2 * N_INTER;
    }
}

// ---------------- 3. place: exact per-(block,bucket) reservations ----------------
// entry = (local_dst << 19) | src   (src < 2^19, local_dst < 1024 -> bits 19..28)
__global__ void place_kernel(const int* __restrict__ uid, const int* __restrict__ iid,
                             u32* __restrict__ bucket_cursor, u32* __restrict__ bdata) {
    __shared__ u32 h[NBUCKET];      // pass1: counts; pass2: local cursor
    __shared__ u32 basesh[NBUCKET]; // reserved global base per bucket
    int t = threadIdx.x;
    for (int i = t; i < NBUCKET; i += 256) h[i] = 0;
    __syncthreads();
    int base = blockIdx.x * TILE;
    int end = base + TILE; if (end > N_INTER) end = N_INTER;
    // pass 1: local histogram
    for (int k = base + t; k < end; k += 256) {
        int u = uid[k];
        int it = N_USERS + iid[k];
        atomicAdd(&h[it >> BSHIFT], 1u);
        atomicAdd(&h[u >> BSHIFT], 1u);
    }
    __syncthreads();
    // reserve ranges
    for (int i = t; i < NBUCKET; i += 256) {
        u32 c = h[i];
        basesh[i] = c ? atomicAdd(&bucket_cursor[i], c) : 0u;
        h[i] = 0;
    }
    __syncthreads();
    // pass 2: place
    for (int k = base + t; k < end; k += 256) {
        int u = uid[k];
        int it = N_USERS + iid[k];
        {
            int b = it >> BSHIFT;
            u32 pos = basesh[b] + atomicAdd(&h[b], 1u);
            bdata[pos] = (((u32)(it & (BNODES - 1))) << 19) | (u32)u;
        }
        {
            int b = u >> BSHIFT;
            u32 pos = basesh[b] + atomicAdd(&h[b], 1u);
            bdata[pos] = (((u32)(u & (BNODES - 1))) << 19) | (u32)it;
        }
    }
}

// ---------------- 4. per-bucket CSR finalize: rowptr, dinv, col ----------------
__global__ void csr_kernel(const u32* __restrict__ bstart, const u32* __restrict__ bdata,
                           u32* __restrict__ rowptr, float* __restrict__ dinv,
                           int* __restrict__ col) {
    __shared__ u32 cnt[BNODES];
    __shared__ u32 sb[2][BNODES];
    __shared__ u32 cur[BNODES];
    int b = blockIdx.x;
    int t = threadIdx.x;               // 256 threads
    int nbase = b << BSHIFT;
    u32 bs = bstart[b], be = bstart[b + 1];
    u32 m = be - bs;

    #pragma unroll
    for (int j = 0; j < 4; ++j) cnt[t + j * 256] = 0;
    __syncthreads();
    // pass A: count per local node
    for (u32 e = t; e < m; e += 256) {
        u32 v = bdata[bs + e];
        atomicAdd(&cnt[v >> 19], 1u);
    }
    __syncthreads();
    // inclusive scan of 1024 (Hillis-Steele, 4 elems/thread)
    #pragma unroll
    for (int j = 0; j < 4; ++j) sb[0][t + j * 256] = cnt[t + j * 256];
    __syncthreads();
    int s = 0;
    for (int off = 1; off < BNODES; off <<= 1) {
        #pragma unroll
        for (int j = 0; j < 4; ++j) {
            int idx = t + j * 256;
            u32 v = sb[s][idx];
            if (idx >= off) v += sb[s][idx - off];
            sb[1 - s][idx] = v;
        }
        __syncthreads();
        s = 1 - s;
    }
    // rowptr, dinv, cursors
    #pragma unroll
    for (int j = 0; j < 4; ++j) {
        int idx = t + j * 256;
        int node = nbase + idx;
        u32 c = cnt[idx];
        u32 excl = sb[s][idx] - c;
        cur[idx] = excl;
        if (node < N_NODES) {
            rowptr[node] = bs + excl;
            dinv[node] = (c > 0) ? rsqrtf((float)c) : 0.0f;
        }
    }
    __syncthreads();
    // pass B: place col entries into contiguous [bs, be)
    for (u32 e = t; e < m; e += 256) {
        u32 v = bdata[bs + e];
        u32 ln = v >> 19;
        u32 pos = atomicAdd(&cur[ln], 1u);
        col[bs + pos] = (int)(v & 0x7FFFFu);
    }
}

// ---------------- 5. edge records: (src, dinv[src]) ----------------
__global__ void ecol_kernel(const int* __restrict__ col, const float* __restrict__ dinv,
                            int2* __restrict__ ecol) {
    int e = blockIdx.x * blockDim.x + threadIdx.x;
    if (e < 2 * N_INTER) {
        int s = col[e];
        ecol[e] = make_int2(s, __float_as_int(dinv[s]));
    }
}

// ---------------- init: fp32 inputs -> bf16 layer-0 buffer ----------------
__global__ void init_kernel(const float4* __restrict__ ue, const float4* __restrict__ ie,
                            ushort4* __restrict__ cur) {
    int idx = blockIdx.x * blockDim.x + threadIdx.x;
    if (idx < N_NODES * 16) {
        float4 v = (idx < N_USERS * 16) ? ue[idx] : ie[idx - N_USERS * 16];
        ushort4 h;
        h.x = f2bf(v.x); h.y = f2bf(v.y); h.z = f2bf(v.z); h.w = f2bf(v.w);
        cur[idx] = h;
    }
}

// ---------------- gather SpMM: one wave per 8-node strip ----------------
// Rows of a strip are contiguous in ecol, so ONE 64-edge vector load serves
// ~9.6 rows (avg degree 6.7) instead of one load per row. Row walk is fully
// wave-uniform: rowptr[n0..n0+8] preloaded into SGPRs (unrolled array), batch
// tails masked via uniform selects (masked slots get w=0 and a harmless
// in-bounds gather of chunk edge 0). Per-edge broadcast stays v_readlane.
__global__ void gather_kernel(const u32* __restrict__ rowptr, const int2* __restrict__ ecol,
                              const float* __restrict__ dinv,
                              const bf16_t* __restrict__ cur, bf16_t* __restrict__ nxt) {
    int wid = (blockIdx.x * blockDim.x + threadIdx.x) >> 6;
    int lane = threadIdx.x & 63;
    int n0 = __builtin_amdgcn_readfirstlane(wid * NPW);
    if (n0 >= N_NODES) return;
    u32 rp[NPW + 1];
    #pragma unroll
    for (int i = 0; i <= NPW; ++i) rp[i] = rowptr[n0 + i];   // uniform -> s_loads
    u32 eend = rp[NPW];
    u32 cbase = rp[0];
    int2 e = make_int2(0, 0);
    {
        u32 cc = eend - cbase; if (cc > 64) cc = 64;
        if ((u32)lane < cc) e = ecol[cbase + lane];
    }
    u32 pos = rp[0];
    #pragma unroll
    for (int r = 0; r < NPW; ++r) {
        u32 re = rp[r + 1];
        float acc = 0.0f;
        while (pos < re) {
            u32 cend = cbase + 64;
            u32 lim = re < cend ? re : cend;
            for (u32 p = pos; p < lim; p += 8) {
                #pragma unroll
                for (int k = 0; k < 8; ++k) {
                    u32 ei = p + (u32)k;
                    int lidx = (ei < lim) ? (int)(ei - cbase) : 0;       // uniform select
                    lidx = __builtin_amdgcn_readfirstlane(lidx);
                    int s = __builtin_amdgcn_readlane(e.x, lidx);
                    int wb = (ei < lim) ? __builtin_amdgcn_readlane(e.y, lidx) : 0;
                    acc += __int_as_float(wb) * bf2f(cur[((u32)s << 6) + lane]);
                }
            }
            pos = lim;
            if (pos == cend && pos < eend) {      // advance chunk (wave-uniform)
                cbase = pos;
                u32 cc = eend - cbase; if (cc > 64) cc = 64;
                e = make_int2(0, 0);
                if ((u32)lane < cc) e = ecol[cbase + lane];
            }
        }
        nxt[(((u32)(n0 + r)) << 6) + (u32)lane] = f2bf(dinv[n0 + r] * acc);
    }
}

// ---------------- layer-3 gather fused with final combine ----------------
__global__ void gather_final_kernel(const u32* __restrict__ rowptr, const int2* __restrict__ ecol,
                                    const float* __restrict__ dinv,
                                    const bf16_t* __restrict__ b1, const bf16_t* __restrict__ b2,
                                    const float* __restrict__ ue, const float* __restrict__ ie,
                                    float* __restrict__ out) {
    int wid = (blockIdx.x * blockDim.x + threadIdx.x) >> 6;
    int lane = threadIdx.x & 63;
    int n0 = __builtin_amdgcn_readfirstlane(wid * NPW);
    if (n0 >= N_NODES) return;
    u32 rp[NPW + 1];
    #pragma unroll
    for (int i = 0; i <= NPW; ++i) rp[i] = rowptr[n0 + i];
    u32 eend = rp[NPW];
    u32 cbase = rp[0];
    int2 e = make_int2(0, 0);
    {
        u32 cc = eend - cbase; if (cc > 64) cc = 64;
        if ((u32)lane < cc) e = ecol[cbase + lane];
    }
    u32 pos = rp[0];
    #pragma unroll
    for (int r = 0; r < NPW; ++r) {
        u32 re = rp[r + 1];
        float acc = 0.0f;
        while (pos < re) {
            u32 cend = cbase + 64;
            u32 lim = re < cend ? re : cend;
            for (u32 p = pos; p < lim; p += 8) {
                #pragma unroll
                for (int k = 0; k < 8; ++k) {
                    u32 ei = p + (u32)k;
                    int lidx = (ei < lim) ? (int)(ei - cbase) : 0;
                    lidx = __builtin_amdgcn_readfirstlane(lidx);
                    int s = __builtin_amdgcn_readlane(e.x, lidx);
                    int wb = (ei < lim) ? __builtin_amdgcn_readlane(e.y, lidx) : 0;
                    acc += __int_as_float(wb) * bf2f(b2[((u32)s << 6) + lane]);
                }
            }
            pos = lim;
            if (pos == cend && pos < eend) {
                cbase = pos;
                u32 cc = eend - cbase; if (cc > 64) cc = 64;
                e = make_int2(0, 0);
                if ((u32)lane < cc) e = ecol[cbase + lane];
            }
        }
        int n = n0 + r;
        float rr = dinv[n] * acc;
        u32 o = (((u32)n) << 6) + (u32)lane;
        float e0 = (n < N_USERS) ? ue[o] : ie[o - (u32)N_USERS * DIM];
        out[o] = (e0 + bf2f(b1[o]) + bf2f(b2[o]) + rr) * 0.25f;
    }
}

extern "C" void kernel_launch(void* const* d_in, const int* in_sizes, int n_in,
                              void* d_out, int out_size, void* d_ws, size_t ws_size,
                              hipStream_t stream) {
    const float* ue = (const float*)d_in[0];
    const float* ie = (const float*)d_in[1];
    const int* uid = (const int*)d_in[2];
    const int* iid = (const int*)d_in[3];
    float* out = (float*)d_out;

    char* ws = (char*)d_ws;
    size_t off = 0;
    auto alloc = [&](size_t bytes) { char* p = ws + off; off = (off + bytes + 255) & ~(size_t)255; return p; };
    u32*    bucket_count  = (u32*)alloc((size_t)NBUCKET * 4);
    u32*    bstart        = (u32*)alloc((size_t)(NBUCKET + 1) * 4);
    u32*    bucket_cursor = (u32*)alloc((size_t)NBUCKET * 4);
    u32*    rowptr        = (u32*)alloc((size_t)(N_NODES + 1) * 4);
    float*  dinv          = (float*)alloc((size_t)N_NODES * 4);
    u32*    bdata         = (u32*)alloc((size_t)2 * N_INTER * 4);     // 8 MB
    int*    col           = (int*)alloc((size_t)2 * N_INTER * 4);     // 8 MB
    int2*   ecol          = (int2*)alloc((size_t)2 * N_INTER * 8);    // 16 MB
    bf16_t* buf0          = (bf16_t*)alloc((size_t)N_NODES * DIM * 2);
    bf16_t* buf1          = (bf16_t*)alloc((size_t)N_NODES * DIM * 2);
    bf16_t* buf2          = (bf16_t*)alloc((size_t)N_NODES * DIM * 2);

    // --- CSR build: exact-reservation bucketed, line-friendly writes throughout ---
    hipMemsetAsync(bucket_count, 0, (size_t)NBUCKET * 4, stream);
    hist_kernel<<<NBLK_P, 256, 0, stream>>>(uid, iid, bucket_count);
    scan_kernel<<<1, 512, 0, stream>>>(bucket_count, bstart, bucket_cursor, rowptr);
    place_kernel<<<NBLK_P, 256, 0, stream>>>(uid, iid, bucket_cursor, bdata);
    csr_kernel<<<NBUCKET, 256, 0, stream>>>(bstart, bdata, rowptr, dinv, col);
    ecol_kernel<<<(2 * N_INTER + 255) / 256, 256, 0, stream>>>(col, dinv, ecol);

    // --- init (fp32 -> bf16 layer 0) ---
    init_kernel<<<(N_NODES * 16 + 255) / 256, 256, 0, stream>>>(
        (const float4*)ue, (const float4*)ie, (ushort4*)buf0);

    // --- layers 1,2 gather; layer 3 fused with final combine ---
    gather_kernel<<<(GATHER_THREADS + 255) / 256, 256, 0, stream>>>(rowptr, ecol, dinv, buf0, buf1);
    gather_kernel<<<(GATHER_THREADS + 255) / 256, 256, 0, stream>>>(rowptr, ecol, dinv, buf1, buf2);
    gather_final_kernel<<<(GATHER_THREADS + 255) / 256, 256, 0, stream>>>(
        rowptr, ecol, dinv, buf1, buf2, ue, ie, out);
}